// Round 1
// baseline (539.329 us; speedup 1.0000x reference)
//
#include <hip/hip_runtime.h>
#include <math.h>

// Problem constants
#define NP 8836          // number of patches per image (94*94)
#define PW 94            // patches per row
#define IW 96            // image width/height
#define CH 256           // channels
#define IMG_E (IW*IW*CH) // elements per image (2359296)
#define NTILE 70         // ceil(8836/128)
#define KT 72            // K tiles: 2304/32

typedef _Float16 half8 __attribute__((ext_vector_type(8)));
typedef _Float16 half4 __attribute__((ext_vector_type(4)));
typedef float f32x4 __attribute__((ext_vector_type(4)));

__device__ __forceinline__ unsigned int ordf(float f) {
  unsigned int u = __float_as_uint(f);
  return (u & 0x80000000u) ? ~u : (u | 0x80000000u);
}

typedef const __attribute__((address_space(1))) void GvoidC;
typedef __attribute__((address_space(3))) void Lvoid;
__device__ __forceinline__ void gl16(const void* g, void* l) {
  __builtin_amdgcn_global_load_lds((GvoidC*)g, (Lvoid*)l, 16, 0, 0);
}

// ---------------------------------------------------------------------------
// 1) Convert + transpose [C,H,W] fp32 -> [y][x][c] f16 for both images.
//    idx ordering (y,x,c) => writes coalesced; reads strided but cache-absorbed.
// ---------------------------------------------------------------------------
__global__ void prep_kernel(const float* __restrict__ inA, const float* __restrict__ inB,
                            _Float16* __restrict__ TA, _Float16* __restrict__ TB) {
  int idx = blockIdx.x * 256 + threadIdx.x;   // 0 .. 2*IMG_E-1 exactly
  const float* src; _Float16* dst; int rem;
  if (idx < IMG_E) { src = inA; dst = TA; rem = idx; }
  else             { src = inB; dst = TB; rem = idx - IMG_E; }
  int c  = rem & 255;
  int xy = rem >> 8;
  dst[rem] = (_Float16)src[c * (IW*IW) + xy];
}

// ---------------------------------------------------------------------------
// 2) Per-patch squared norms from the f16 images (consistent with GEMM dtype).
//    One wave per patch; style patches also get sqrt and reciprocal-sqrt.
// ---------------------------------------------------------------------------
__global__ void norms_kernel(const _Float16* __restrict__ TA, const _Float16* __restrict__ TB,
                             float* __restrict__ rnormS, float* __restrict__ normS,
                             float* __restrict__ normsqS, float* __restrict__ synsq) {
  int wid  = blockIdx.x * 4 + (threadIdx.x >> 6);
  int lane = threadIdx.x & 63;
  bool isStyle = wid < NP;
  int p = isStyle ? wid : wid - NP;
  if (p >= NP) return;
  const _Float16* T = isStyle ? TB : TA;
  int pi = p / PW, pj = p % PW;
  float s = 0.f;
  #pragma unroll
  for (int kh = 0; kh < 3; ++kh) {
    #pragma unroll
    for (int kw = 0; kw < 3; ++kw) {
      const half4* v4 = (const half4*)(T + (size_t)((pi + kh) * IW + (pj + kw)) * CH) + lane;
      half4 v = *v4;
      s += (float)v[0]*(float)v[0] + (float)v[1]*(float)v[1]
         + (float)v[2]*(float)v[2] + (float)v[3]*(float)v[3];
    }
  }
  #pragma unroll
  for (int m = 32; m >= 1; m >>= 1) s += __shfl_xor(s, m, 64);
  if (lane == 0) {
    if (isStyle) {
      normsqS[p] = s;
      float n = sqrtf(s);
      normS[p]  = n;
      rnormS[p] = 1.f / n;
    } else {
      synsq[p] = s;
    }
  }
}

// ---------------------------------------------------------------------------
// 3) Implicit-im2col GEMM (Q x S x 2304) with fused argmax epilogue.
//    128x128 tile, BK=32, 4 waves (2x2), mfma_f32_16x16x32_f16.
//    K ordered (kh,kw,c): contiguous 256-f16 chunks in the [y][x][c] layout,
//    so global_load_lds width=16 staging is fully coalesced.
// ---------------------------------------------------------------------------
__global__ __launch_bounds__(256) void gemm_argmax_kernel(
    const _Float16* __restrict__ TA, const _Float16* __restrict__ TB,
    const float* __restrict__ rnormS, unsigned long long* __restrict__ best) {
  __shared__ _Float16 As[128 * 32];
  __shared__ _Float16 Bs[128 * 32];

  int pid = blockIdx.x;
  int mt = pid % NTILE, nt = pid / NTILE;
  int q0 = mt * 128, s0 = nt * 128;
  int t = threadIdx.x, lane = t & 63, wave = t >> 6;
  int wm = wave >> 1, wn = wave & 1;

  // Staging: thread t loads 16B chunks for rows r=t>>2 and r+64, chunk cs=t&3.
  int r = t >> 2, cs = t & 3;
  int qa0 = q0 + r;      if (qa0 > NP - 1) qa0 = NP - 1;
  int qa1 = q0 + r + 64; if (qa1 > NP - 1) qa1 = NP - 1;
  int sa0 = s0 + r;      if (sa0 > NP - 1) sa0 = NP - 1;
  int sa1 = s0 + r + 64; if (sa1 > NP - 1) sa1 = NP - 1;
  // byte offset of patch (pi,pj) row base in the [y][x][c] f16 image
  const char* gA0 = (const char*)TA + (size_t)((qa0 / PW) * IW + (qa0 % PW)) * (CH * 2) + cs * 16;
  const char* gA1 = (const char*)TA + (size_t)((qa1 / PW) * IW + (qa1 % PW)) * (CH * 2) + cs * 16;
  const char* gB0 = (const char*)TB + (size_t)((sa0 / PW) * IW + (sa0 % PW)) * (CH * 2) + cs * 16;
  const char* gB1 = (const char*)TB + (size_t)((sa1 / PW) * IW + (sa1 % PW)) * (CH * 2) + cs * 16;
  char* lA0 = (char*)As + t * 16;
  char* lA1 = lA0 + 4096;
  char* lB0 = (char*)Bs + t * 16;
  char* lB1 = lB0 + 4096;

  f32x4 acc[4][4];
  #pragma unroll
  for (int mi = 0; mi < 4; ++mi)
    #pragma unroll
    for (int ni = 0; ni < 4; ++ni)
      acc[mi][ni] = (f32x4){0.f, 0.f, 0.f, 0.f};

  const _Float16* Ap = As + (wm * 64 + (lane & 15)) * 32 + (lane >> 4) * 8;
  const _Float16* Bp = Bs + (wn * 64 + (lane & 15)) * 32 + (lane >> 4) * 8;

  for (int kt = 0; kt < KT; ++kt) {
    int chunk = kt >> 3;
    int kh = chunk / 3, kw = chunk - kh * 3;
    int choff = (kh * IW + kw) * (CH * 2) + (kt & 7) * 64;  // bytes
    if (kt) __syncthreads();
    gl16(gA0 + choff, lA0);
    gl16(gA1 + choff, lA1);
    gl16(gB0 + choff, lB0);
    gl16(gB1 + choff, lB1);
    __syncthreads();

    half8 af[4], bf[4];
    #pragma unroll
    for (int mi = 0; mi < 4; ++mi) af[mi] = *(const half8*)(Ap + mi * 16 * 32);
    #pragma unroll
    for (int ni = 0; ni < 4; ++ni) bf[ni] = *(const half8*)(Bp + ni * 16 * 32);
    #pragma unroll
    for (int mi = 0; mi < 4; ++mi)
      #pragma unroll
      for (int ni = 0; ni < 4; ++ni)
        acc[mi][ni] = __builtin_amdgcn_mfma_f32_16x16x32_f16(af[mi], bf[ni], acc[mi][ni], 0, 0, 0);
  }

  // Epilogue: resp = dot * rnorm[s]; track (max resp, min idx) per q-row.
  int col = lane & 15, quad = lane >> 4;
  float rn[4]; int sc[4]; bool sv[4];
  #pragma unroll
  for (int ni = 0; ni < 4; ++ni) {
    int s = s0 + wn * 64 + ni * 16 + col;
    sc[ni] = s;
    sv[ni] = (s < NP);
    rn[ni] = sv[ni] ? rnormS[s] : 0.f;
  }
  #pragma unroll
  for (int mi = 0; mi < 4; ++mi) {
    #pragma unroll
    for (int rg = 0; rg < 4; ++rg) {
      unsigned long long p = 0ull;
      #pragma unroll
      for (int ni = 0; ni < 4; ++ni) {
        float v = acc[mi][ni][rg] * rn[ni];
        unsigned long long cand =
            ((unsigned long long)ordf(v) << 32) |
            (unsigned long long)(0xFFFFFFFFu - (unsigned)sc[ni]);
        cand = sv[ni] ? cand : 0ull;
        if (cand > p) p = cand;
      }
      #pragma unroll
      for (int sh = 8; sh >= 1; sh >>= 1) {
        unsigned long long o = __shfl_xor(p, sh, 64);
        if (o > p) p = o;
      }
      int q = q0 + wm * 64 + mi * 16 + quad * 4 + rg;
      if (col == 0 && q < NP) atomicMax(best + q, p);
    }
  }
}

// ---------------------------------------------------------------------------
// 4) Final loss: loss = mean_q (synsq[q] - 2*dot + normsq[nn]) / 2304
// ---------------------------------------------------------------------------
__global__ void finalize_kernel(const unsigned long long* __restrict__ best,
                                const float* __restrict__ normS,
                                const float* __restrict__ normsqS,
                                const float* __restrict__ synsq,
                                float* __restrict__ out) {
  __shared__ float sm[256];
  int t = threadIdx.x;
  float accum = 0.f;
  for (int q = t; q < NP; q += 256) {
    unsigned long long p = best[q];
    unsigned int o   = (unsigned int)(p >> 32);
    unsigned int idx = 0xFFFFFFFFu - (unsigned int)(p & 0xFFFFFFFFull);
    unsigned int u   = (o & 0x80000000u) ? (o & 0x7FFFFFFFu) : ~o;
    float resp = __uint_as_float(u);
    float dot  = resp * normS[idx];
    accum += synsq[q] - 2.f * dot + normsqS[idx];
  }
  sm[t] = accum;
  __syncthreads();
  for (int s = 128; s >= 1; s >>= 1) {
    if (t < s) sm[t] += sm[t + s];
    __syncthreads();
  }
  if (t == 0) out[0] = sm[0] / ((float)NP * 2304.f);
}

// ---------------------------------------------------------------------------
extern "C" void kernel_launch(void* const* d_in, const int* in_sizes, int n_in,
                              void* d_out, int out_size, void* d_ws, size_t ws_size,
                              hipStream_t stream) {
  const float* inA = (const float*)d_in[0];  // input  (synthesis)
  const float* inB = (const float*)d_in[1];  // target (style)
  float* out = (float*)d_out;

  char* ws = (char*)d_ws;
  _Float16* TA = (_Float16*)ws;                       // 4,718,592 B
  _Float16* TB = (_Float16*)(ws + 4718592);           // 4,718,592 B
  float* rnormS  = (float*)(ws + 9437184);            // 35,344 B
  float* normS   = (float*)(ws + 9437184 + 35344);
  float* normsqS = (float*)(ws + 9437184 + 70688);
  float* synsq   = (float*)(ws + 9437184 + 106032);
  unsigned long long* best = (unsigned long long*)(ws + 9437184 + 141376); // 70,688 B

  hipMemsetAsync(best, 0, (size_t)NP * 8, stream);
  prep_kernel<<<dim3(2 * IMG_E / 256), dim3(256), 0, stream>>>(inA, inB, TA, TB);
  norms_kernel<<<dim3((2 * NP + 3) / 4), dim3(256), 0, stream>>>(TA, TB, rnormS, normS, normsqS, synsq);
  gemm_argmax_kernel<<<dim3(NTILE * NTILE), dim3(256), 0, stream>>>(TA, TB, rnormS, best);
  finalize_kernel<<<dim3(1), dim3(256), 0, stream>>>(best, normS, normsqS, synsq, out);
}

// Round 2
// 534.356 us; speedup vs baseline: 1.0093x; 1.0093x over previous
//
#include <hip/hip_runtime.h>
#include <math.h>

// Problem constants
#define NP 8836          // number of patches per image (94*94)
#define PW 94            // patches per row
#define IW 96            // image width/height
#define CH 256           // channels
#define IMG_E (IW*IW*CH) // elements per image (2359296)
#define NTILE 70         // ceil(8836/128)
#define KT 72            // K tiles: 2304/32

typedef _Float16 half8 __attribute__((ext_vector_type(8)));
typedef _Float16 half4 __attribute__((ext_vector_type(4)));
typedef float f32x4 __attribute__((ext_vector_type(4)));

__device__ __forceinline__ unsigned int ordf(float f) {
  unsigned int u = __float_as_uint(f);
  return (u & 0x80000000u) ? ~u : (u | 0x80000000u);
}

typedef const __attribute__((address_space(1))) void GvoidC;
typedef __attribute__((address_space(3))) void Lvoid;
__device__ __forceinline__ void gl16(const void* g, void* l) {
  __builtin_amdgcn_global_load_lds((GvoidC*)g, (Lvoid*)l, 16, 0, 0);
}

// ---------------------------------------------------------------------------
// 1) Convert + transpose [C, 9216] fp32 -> [9216, C] f16 for both images.
//    LDS tile transpose: 64 xy x 64 c per block, both global phases coalesced.
//    Per image: 144 xy-tiles x 4 c-tiles = 576 blocks.
// ---------------------------------------------------------------------------
__global__ __launch_bounds__(256) void prep_kernel(
    const float* __restrict__ inA, const float* __restrict__ inB,
    _Float16* __restrict__ TA, _Float16* __restrict__ TB) {
  __shared__ float tile[64][65];   // pad 65: transpose read conflict-free
  int bid = blockIdx.x;            // [0, 1152)
  const float* src; _Float16* dst;
  if (bid < 576) { src = inA; dst = TA; }
  else           { src = inB; dst = TB; bid -= 576; }
  int cT  = bid & 3;        // c-tile   [0,4)
  int xyT = bid >> 2;       // xy-tile  [0,144)
  int t = threadIdx.x;
  int l = t & 63, h = t >> 6;   // lane-in-64, quarter

  // Read: 64 c rows x 64 xy, coalesced along xy.
  #pragma unroll
  for (int i = 0; i < 16; ++i) {
    int c = h * 16 + i;
    tile[c][l] = src[(size_t)(cT * 64 + c) * (IW * IW) + xyT * 64 + l];
  }
  __syncthreads();
  // Write: 64 xy rows x 64 c, coalesced along c.
  #pragma unroll
  for (int i = 0; i < 16; ++i) {
    int xy = h * 16 + i;
    dst[(size_t)(xyT * 64 + xy) * CH + cT * 64 + l] = (_Float16)tile[l][xy];
  }
}

// ---------------------------------------------------------------------------
// 2) Per-patch squared norms from the f16 images (consistent with GEMM dtype).
// ---------------------------------------------------------------------------
__global__ void norms_kernel(const _Float16* __restrict__ TA, const _Float16* __restrict__ TB,
                             float* __restrict__ rnormS, float* __restrict__ normS,
                             float* __restrict__ normsqS, float* __restrict__ synsq) {
  int wid  = blockIdx.x * 4 + (threadIdx.x >> 6);
  int lane = threadIdx.x & 63;
  bool isStyle = wid < NP;
  int p = isStyle ? wid : wid - NP;
  if (p >= NP) return;
  const _Float16* T = isStyle ? TB : TA;
  int pi = p / PW, pj = p % PW;
  float s = 0.f;
  #pragma unroll
  for (int kh = 0; kh < 3; ++kh) {
    #pragma unroll
    for (int kw = 0; kw < 3; ++kw) {
      const half4* v4 = (const half4*)(T + (size_t)((pi + kh) * IW + (pj + kw)) * CH) + lane;
      half4 v = *v4;
      s += (float)v[0]*(float)v[0] + (float)v[1]*(float)v[1]
         + (float)v[2]*(float)v[2] + (float)v[3]*(float)v[3];
    }
  }
  #pragma unroll
  for (int m = 32; m >= 1; m >>= 1) s += __shfl_xor(s, m, 64);
  if (lane == 0) {
    if (isStyle) {
      normsqS[p] = s;
      float n = sqrtf(s);
      normS[p]  = n;
      rnormS[p] = 1.f / n;
    } else {
      synsq[p] = s;
    }
  }
}

// ---------------------------------------------------------------------------
// 3) Implicit-im2col GEMM (Q x S x 2304) with fused argmax epilogue.
//    128x128 tile, BK=32, 4 waves (2x2), mfma_f32_16x16x32_f16.
//    LDS layout XOR-swizzled: chunk q of row r lives at slot q ^ swz(r),
//    swz(r) = (r ^ (r>>2)) & 3. Staging stays lane-contiguous (required by
//    global_load_lds) AND 64B-coalesced per row; fragment reads become
//    canonical 2-lane/bank-group (conflict-free, m136).
// ---------------------------------------------------------------------------
__global__ __launch_bounds__(256) void gemm_argmax_kernel(
    const _Float16* __restrict__ TA, const _Float16* __restrict__ TB,
    const float* __restrict__ rnormS, unsigned long long* __restrict__ best) {
  __shared__ _Float16 As[128 * 32];
  __shared__ _Float16 Bs[128 * 32];

  int pid = blockIdx.x;
  int mt = pid % NTILE, nt = pid / NTILE;
  int q0 = mt * 128, s0 = nt * 128;
  int t = threadIdx.x, lane = t & 63, wave = t >> 6;
  int wm = wave >> 1, wn = wave & 1;

  // Staging: thread t covers rows r=t>>2 and r+64. LDS slot cs=t&3 receives
  // global chunk qc = cs ^ swz(r) (swz identical for r and r+64).
  int r = t >> 2, cs = t & 3;
  int qc = cs ^ ((r ^ (r >> 2)) & 3);
  int qa0 = q0 + r;      if (qa0 > NP - 1) qa0 = NP - 1;
  int qa1 = q0 + r + 64; if (qa1 > NP - 1) qa1 = NP - 1;
  int sa0 = s0 + r;      if (sa0 > NP - 1) sa0 = NP - 1;
  int sa1 = s0 + r + 64; if (sa1 > NP - 1) sa1 = NP - 1;
  const char* gA0 = (const char*)TA + (size_t)((qa0 / PW) * IW + (qa0 % PW)) * (CH * 2) + qc * 16;
  const char* gA1 = (const char*)TA + (size_t)((qa1 / PW) * IW + (qa1 % PW)) * (CH * 2) + qc * 16;
  const char* gB0 = (const char*)TB + (size_t)((sa0 / PW) * IW + (sa0 % PW)) * (CH * 2) + qc * 16;
  const char* gB1 = (const char*)TB + (size_t)((sa1 / PW) * IW + (sa1 % PW)) * (CH * 2) + qc * 16;
  char* lA0 = (char*)As + t * 16;
  char* lA1 = lA0 + 4096;
  char* lB0 = (char*)Bs + t * 16;
  char* lB1 = lB0 + 4096;

  f32x4 acc[4][4];
  #pragma unroll
  for (int mi = 0; mi < 4; ++mi)
    #pragma unroll
    for (int ni = 0; ni < 4; ++ni)
      acc[mi][ni] = (f32x4){0.f, 0.f, 0.f, 0.f};

  // Fragment read: lane wants (row16 = lane&15, chunk q = lane>>4); its LDS
  // slot is q ^ swz(row16) — constant per lane (swz uses row bits 0..3 only).
  int slot = (lane >> 4) ^ ((lane ^ (lane >> 2)) & 3);
  const _Float16* Ap = As + (wm * 64 + (lane & 15)) * 32 + slot * 8;
  const _Float16* Bp = Bs + (wn * 64 + (lane & 15)) * 32 + slot * 8;

  for (int kt = 0; kt < KT; ++kt) {
    int chunk = kt >> 3;
    int kh = chunk / 3, kw = chunk - kh * 3;
    int choff = (kh * IW + kw) * (CH * 2) + (kt & 7) * 64;  // bytes
    if (kt) __syncthreads();
    gl16(gA0 + choff, lA0);
    gl16(gA1 + choff, lA1);
    gl16(gB0 + choff, lB0);
    gl16(gB1 + choff, lB1);
    __syncthreads();

    half8 af[4], bf[4];
    #pragma unroll
    for (int mi = 0; mi < 4; ++mi) af[mi] = *(const half8*)(Ap + mi * 16 * 32);
    #pragma unroll
    for (int ni = 0; ni < 4; ++ni) bf[ni] = *(const half8*)(Bp + ni * 16 * 32);
    #pragma unroll
    for (int mi = 0; mi < 4; ++mi)
      #pragma unroll
      for (int ni = 0; ni < 4; ++ni)
        acc[mi][ni] = __builtin_amdgcn_mfma_f32_16x16x32_f16(af[mi], bf[ni], acc[mi][ni], 0, 0, 0);
  }

  // Epilogue: resp = dot * rnorm[s]; track (max resp, min idx) per q-row.
  int col = lane & 15, quad = lane >> 4;
  float rn[4]; int sc[4]; bool sv[4];
  #pragma unroll
  for (int ni = 0; ni < 4; ++ni) {
    int s = s0 + wn * 64 + ni * 16 + col;
    sc[ni] = s;
    sv[ni] = (s < NP);
    rn[ni] = sv[ni] ? rnormS[s] : 0.f;
  }
  #pragma unroll
  for (int mi = 0; mi < 4; ++mi) {
    #pragma unroll
    for (int rg = 0; rg < 4; ++rg) {
      unsigned long long p = 0ull;
      #pragma unroll
      for (int ni = 0; ni < 4; ++ni) {
        float v = acc[mi][ni][rg] * rn[ni];
        unsigned long long cand =
            ((unsigned long long)ordf(v) << 32) |
            (unsigned long long)(0xFFFFFFFFu - (unsigned)sc[ni]);
        cand = sv[ni] ? cand : 0ull;
        if (cand > p) p = cand;
      }
      #pragma unroll
      for (int sh = 8; sh >= 1; sh >>= 1) {
        unsigned long long o = __shfl_xor(p, sh, 64);
        if (o > p) p = o;
      }
      int q = q0 + wm * 64 + mi * 16 + quad * 4 + rg;
      if (col == 0 && q < NP) atomicMax(best + q, p);
    }
  }
}

// ---------------------------------------------------------------------------
// 4) Final loss: loss = mean_q (synsq[q] - 2*dot + normsq[nn]) / 2304
// ---------------------------------------------------------------------------
__global__ void finalize_kernel(const unsigned long long* __restrict__ best,
                                const float* __restrict__ normS,
                                const float* __restrict__ normsqS,
                                const float* __restrict__ synsq,
                                float* __restrict__ out) {
  __shared__ float sm[256];
  int t = threadIdx.x;
  float accum = 0.f;
  for (int q = t; q < NP; q += 256) {
    unsigned long long p = best[q];
    unsigned int o   = (unsigned int)(p >> 32);
    unsigned int idx = 0xFFFFFFFFu - (unsigned int)(p & 0xFFFFFFFFull);
    unsigned int u   = (o & 0x80000000u) ? (o & 0x7FFFFFFFu) : ~o;
    float resp = __uint_as_float(u);
    float dot  = resp * normS[idx];
    accum += synsq[q] - 2.f * dot + normsqS[idx];
  }
  sm[t] = accum;
  __syncthreads();
  for (int s = 128; s >= 1; s >>= 1) {
    if (t < s) sm[t] += sm[t + s];
    __syncthreads();
  }
  if (t == 0) out[0] = sm[0] / ((float)NP * 2304.f);
}

// ---------------------------------------------------------------------------
extern "C" void kernel_launch(void* const* d_in, const int* in_sizes, int n_in,
                              void* d_out, int out_size, void* d_ws, size_t ws_size,
                              hipStream_t stream) {
  const float* inA = (const float*)d_in[0];  // input  (synthesis)
  const float* inB = (const float*)d_in[1];  // target (style)
  float* out = (float*)d_out;

  char* ws = (char*)d_ws;
  _Float16* TA = (_Float16*)ws;                       // 4,718,592 B
  _Float16* TB = (_Float16*)(ws + 4718592);           // 4,718,592 B
  float* rnormS  = (float*)(ws + 9437184);
  float* normS   = (float*)(ws + 9437184 + 35344);
  float* normsqS = (float*)(ws + 9437184 + 70688);
  float* synsq   = (float*)(ws + 9437184 + 106032);
  unsigned long long* best = (unsigned long long*)(ws + 9437184 + 141376);

  hipMemsetAsync(best, 0, (size_t)NP * 8, stream);
  prep_kernel<<<dim3(1152), dim3(256), 0, stream>>>(inA, inB, TA, TB);
  norms_kernel<<<dim3((2 * NP + 3) / 4), dim3(256), 0, stream>>>(TA, TB, rnormS, normS, normsqS, synsq);
  gemm_argmax_kernel<<<dim3(NTILE * NTILE), dim3(256), 0, stream>>>(TA, TB, rnormS, best);
  finalize_kernel<<<dim3(1), dim3(256), 0, stream>>>(best, normS, normsqS, synsq, out);
}